// Round 1
// baseline (486.130 us; speedup 1.0000x reference)
//
#include <hip/hip_runtime.h>
#include <math.h>

// Problem constants
#define BATCH 4
#define TSEQ  2048
#define CEMB  1024
#define NHEAD 16
#define HD    64
// derived
#define MROWS (BATCH * TSEQ)   // 8192

typedef _Float16 half8 __attribute__((ext_vector_type(8)));
typedef _Float16 half4 __attribute__((ext_vector_type(4)));
typedef float    floatx4 __attribute__((ext_vector_type(4)));

// ---------------------------------------------------------------------------
// Kernel 1: qkv = x @ W_attn^T, fp32 inputs cast to fp16 during LDS staging.
// Epilogue scatters: q16[b][h][t][d], k16[b][h][t][d], v16[b][h][d][t] (V^T).
// Tile: 128x128, BK=32, 4 waves (2x2 of 64x64), f16 MFMA 16x16x32.
// ---------------------------------------------------------------------------
__global__ __launch_bounds__(256)
void qkv_gemm(const float* __restrict__ A, const float* __restrict__ B,
              _Float16* __restrict__ q16, _Float16* __restrict__ k16,
              _Float16* __restrict__ v16)
{
    __shared__ __align__(16) _Float16 As[128 * 40];  // pad 32 -> 40 halves
    __shared__ __align__(16) _Float16 Bs[128 * 40];
    const int tid  = threadIdx.x;
    const int lane = tid & 63;
    const int wave = tid >> 6;
    const int wm = wave & 1, wn = wave >> 1;
    const int m0 = blockIdx.y * 128;
    const int n0 = blockIdx.x * 128;
    const int l15 = lane & 15;
    const int koff = (lane >> 4) << 3;

    floatx4 acc[4][4];
#pragma unroll
    for (int i = 0; i < 4; ++i)
#pragma unroll
        for (int j = 0; j < 4; ++j) acc[i][j] = (floatx4){0.f, 0.f, 0.f, 0.f};

    for (int kk = 0; kk < CEMB; kk += 32) {
        __syncthreads();
#pragma unroll
        for (int i = 0; i < 4; ++i) {
            int c = tid + i * 256;          // 0..1023 = 128 rows x 8 chunks(4 floats)
            int row = c >> 3;
            int col = (c & 7) << 2;
            float4 av = *(const float4*)(A + (size_t)(m0 + row) * CEMB + kk + col);
            half4 ah = { (_Float16)av.x, (_Float16)av.y, (_Float16)av.z, (_Float16)av.w };
            *(half4*)(As + row * 40 + col) = ah;
            float4 bv = *(const float4*)(B + (size_t)(n0 + row) * CEMB + kk + col);
            half4 bh = { (_Float16)bv.x, (_Float16)bv.y, (_Float16)bv.z, (_Float16)bv.w };
            *(half4*)(Bs + row * 40 + col) = bh;
        }
        __syncthreads();
        half8 af[4], bf[4];
#pragma unroll
        for (int mt = 0; mt < 4; ++mt)
            af[mt] = *(const half8*)(As + (wm * 64 + mt * 16 + l15) * 40 + koff);
#pragma unroll
        for (int nt = 0; nt < 4; ++nt)
            bf[nt] = *(const half8*)(Bs + (wn * 64 + nt * 16 + l15) * 40 + koff);
#pragma unroll
        for (int mt = 0; mt < 4; ++mt)
#pragma unroll
            for (int nt = 0; nt < 4; ++nt)
                acc[mt][nt] = __builtin_amdgcn_mfma_f32_16x16x32_f16(af[mt], bf[nt], acc[mt][nt], 0, 0, 0);
    }

    // Epilogue: scatter into q/k/v fp16 buffers.
    const int rbase = (lane >> 4) << 2;
#pragma unroll
    for (int mt = 0; mt < 4; ++mt) {
#pragma unroll
        for (int nt = 0; nt < 4; ++nt) {
            int gn = n0 + wn * 64 + nt * 16 + l15;
#pragma unroll
            for (int r = 0; r < 4; ++r) {
                int gm = m0 + wm * 64 + mt * 16 + rbase + r;
                _Float16 hv = (_Float16)acc[mt][nt][r];
                int b = gm >> 11, t = gm & (TSEQ - 1);
                if (gn < CEMB) {
                    int h = gn >> 6, d = gn & 63;
                    q16[(((size_t)(b * NHEAD + h)) * TSEQ + t) * HD + d] = hv;
                } else if (gn < 2 * CEMB) {
                    int c2 = gn - CEMB;
                    int h = c2 >> 6, d = c2 & 63;
                    k16[(((size_t)(b * NHEAD + h)) * TSEQ + t) * HD + d] = hv;
                } else {
                    int c2 = gn - 2 * CEMB;
                    int h = c2 >> 6, d = c2 & 63;
                    v16[(((size_t)(b * NHEAD + h)) * HD + d) * TSEQ + t] = hv;  // transposed
                }
            }
        }
    }
}

// ---------------------------------------------------------------------------
// Kernel 2: flash-style causal attention, one (b,h,qtile=64) per block.
// 4 waves, each owns 16 q-rows. K-tiles of 64 keys. fp32 online softmax.
// Faithful to reference: logits SCALED BY sqrt(hd)=8 (multiply).
// ---------------------------------------------------------------------------
__global__ __launch_bounds__(256)
void attn_fwd(const _Float16* __restrict__ q16, const _Float16* __restrict__ k16,
              const _Float16* __restrict__ v16, _Float16* __restrict__ o16)
{
    __shared__ __align__(16) _Float16 Qs[64 * 72];
    __shared__ __align__(16) _Float16 Ks[64 * 72];
    __shared__ __align__(16) _Float16 Vs[64 * 72];   // [d][t]
    __shared__ __align__(16) _Float16 Ps[4 * 16 * 72];
    const int tid = threadIdx.x, lane = tid & 63, wave = tid >> 6;
    const int qt = blockIdx.x;          // 0..31
    const int bh = blockIdx.y;          // 0..63
    const int b = bh >> 4, h = bh & 15;
    const int q0 = qt * 64;
    const int l15 = lane & 15;
    const int koff = (lane >> 4) << 3;

    const _Float16* qp = q16 + ((size_t)bh * TSEQ + q0) * HD;
    const _Float16* kp = k16 + (size_t)bh * TSEQ * HD;
    const _Float16* vp = v16 + (size_t)bh * HD * TSEQ;

#pragma unroll
    for (int i = 0; i < 2; ++i) {
        int c = tid + i * 256;          // 64 rows x 8 chunks(8 halves)
        int row = c >> 3, ch = (c & 7) << 3;
        *(half8*)(Qs + row * 72 + ch) = *(const half8*)(qp + row * HD + ch);
    }
    __syncthreads();
    half8 qf0 = *(const half8*)(Qs + (wave * 16 + l15) * 72 + koff);
    half8 qf1 = *(const half8*)(Qs + (wave * 16 + l15) * 72 + 32 + koff);

    float m_i[4], l_i[4];
    floatx4 o[4];
#pragma unroll
    for (int r = 0; r < 4; ++r) { m_i[r] = -INFINITY; l_i[r] = 0.f; }
#pragma unroll
    for (int nt = 0; nt < 4; ++nt) o[nt] = (floatx4){0.f, 0.f, 0.f, 0.f};

    _Float16* pw = Ps + wave * 16 * 72;
    const int qrow = q0 + wave * 16 + ((lane >> 4) << 2);   // + r = global query row

    for (int kt = 0; kt <= qt; ++kt) {
        const int kt0 = kt * 64;
        __syncthreads();   // previous iteration's Ks/Vs reads done
#pragma unroll
        for (int i = 0; i < 2; ++i) {
            int c = tid + i * 256;
            int row = c >> 3, ch = (c & 7) << 3;
            *(half8*)(Ks + row * 72 + ch) = *(const half8*)(kp + (size_t)(kt0 + row) * HD + ch);
            *(half8*)(Vs + row * 72 + ch) = *(const half8*)(vp + (size_t)row * TSEQ + kt0 + ch);
        }
        __syncthreads();

        // S = (Q K^T) * 8, masked on diagonal tile
        floatx4 s[4];
#pragma unroll
        for (int nt = 0; nt < 4; ++nt) {
            half8 kf0 = *(const half8*)(Ks + (nt * 16 + l15) * 72 + koff);
            half8 kf1 = *(const half8*)(Ks + (nt * 16 + l15) * 72 + 32 + koff);
            floatx4 z = (floatx4){0.f, 0.f, 0.f, 0.f};
            z = __builtin_amdgcn_mfma_f32_16x16x32_f16(qf0, kf0, z, 0, 0, 0);
            z = __builtin_amdgcn_mfma_f32_16x16x32_f16(qf1, kf1, z, 0, 0, 0);
            s[nt] = z;
        }
        if (kt == qt) {
#pragma unroll
            for (int nt = 0; nt < 4; ++nt)
#pragma unroll
                for (int r = 0; r < 4; ++r) {
                    float sv = s[nt][r] * 8.0f;
                    if (kt0 + nt * 16 + l15 > qrow + r) sv = -INFINITY;
                    s[nt][r] = sv;
                }
        } else {
#pragma unroll
            for (int nt = 0; nt < 4; ++nt)
#pragma unroll
                for (int r = 0; r < 4; ++r) s[nt][r] *= 8.0f;
        }

        // online softmax (rows live in 16-lane groups: lanes with same lane>>4)
        float alpha[4];
#pragma unroll
        for (int r = 0; r < 4; ++r) {
            float v = fmaxf(fmaxf(s[0][r], s[1][r]), fmaxf(s[2][r], s[3][r]));
#pragma unroll
            for (int off = 1; off < 16; off <<= 1)
                v = fmaxf(v, __shfl_xor(v, off, 64));
            float mn = fmaxf(m_i[r], v);
            alpha[r] = __expf(m_i[r] - mn);
            m_i[r] = mn;
        }
        float rsum[4] = {0.f, 0.f, 0.f, 0.f};
#pragma unroll
        for (int nt = 0; nt < 4; ++nt)
#pragma unroll
            for (int r = 0; r < 4; ++r) {
                float p = __expf(s[nt][r] - m_i[r]);
                s[nt][r] = p;
                rsum[r] += p;
            }
#pragma unroll
        for (int r = 0; r < 4; ++r) {
            float v = rsum[r];
#pragma unroll
            for (int off = 1; off < 16; off <<= 1)
                v += __shfl_xor(v, off, 64);
            l_i[r] = l_i[r] * alpha[r] + v;
        }
#pragma unroll
        for (int nt = 0; nt < 4; ++nt)
#pragma unroll
            for (int r = 0; r < 4; ++r) o[nt][r] *= alpha[r];

        // P: C-layout -> A-layout via per-wave LDS round-trip
#pragma unroll
        for (int nt = 0; nt < 4; ++nt)
#pragma unroll
            for (int r = 0; r < 4; ++r)
                pw[(((lane >> 4) << 2) + r) * 72 + nt * 16 + l15] = (_Float16)s[nt][r];
        __syncthreads();
        half8 pf0 = *(const half8*)(pw + l15 * 72 + koff);
        half8 pf1 = *(const half8*)(pw + l15 * 72 + 32 + koff);
#pragma unroll
        for (int nt = 0; nt < 4; ++nt) {
            half8 vf0 = *(const half8*)(Vs + (nt * 16 + l15) * 72 + koff);
            half8 vf1 = *(const half8*)(Vs + (nt * 16 + l15) * 72 + 32 + koff);
            o[nt] = __builtin_amdgcn_mfma_f32_16x16x32_f16(pf0, vf0, o[nt], 0, 0, 0);
            o[nt] = __builtin_amdgcn_mfma_f32_16x16x32_f16(pf1, vf1, o[nt], 0, 0, 0);
        }
    }

    // normalize + store [B,T,C] fp16
#pragma unroll
    for (int nt = 0; nt < 4; ++nt)
#pragma unroll
        for (int r = 0; r < 4; ++r) {
            float v = o[nt][r] / l_i[r];
            int t = qrow + r;
            int d = nt * 16 + l15;
            o16[((size_t)(b * TSEQ + t)) * CEMB + h * HD + d] = (_Float16)v;
        }
}

// ---------------------------------------------------------------------------
// Kernel 3: y = attn_out(fp16) @ W_proj^T + b_proj, fp32 output.
// ---------------------------------------------------------------------------
__global__ __launch_bounds__(256)
void proj_gemm(const _Float16* __restrict__ A, const float* __restrict__ B,
               const float* __restrict__ bias, float* __restrict__ out)
{
    __shared__ __align__(16) _Float16 As[128 * 40];
    __shared__ __align__(16) _Float16 Bs[128 * 40];
    const int tid  = threadIdx.x;
    const int lane = tid & 63;
    const int wave = tid >> 6;
    const int wm = wave & 1, wn = wave >> 1;
    const int m0 = blockIdx.y * 128;
    const int n0 = blockIdx.x * 128;
    const int l15 = lane & 15;
    const int koff = (lane >> 4) << 3;

    floatx4 acc[4][4];
#pragma unroll
    for (int i = 0; i < 4; ++i)
#pragma unroll
        for (int j = 0; j < 4; ++j) acc[i][j] = (floatx4){0.f, 0.f, 0.f, 0.f};

    for (int kk = 0; kk < CEMB; kk += 32) {
        __syncthreads();
#pragma unroll
        for (int i = 0; i < 2; ++i) {   // A is already fp16: 128x32 halves
            int c = tid + i * 256;      // 0..511 = 128 rows x 4 chunks(8 halves)
            int row = c >> 2, col = (c & 3) << 3;
            *(half8*)(As + row * 40 + col) =
                *(const half8*)(A + (size_t)(m0 + row) * CEMB + kk + col);
        }
#pragma unroll
        for (int i = 0; i < 4; ++i) {   // B fp32 -> fp16
            int c = tid + i * 256;
            int row = c >> 3, col = (c & 7) << 2;
            float4 bv = *(const float4*)(B + (size_t)(n0 + row) * CEMB + kk + col);
            half4 bh = { (_Float16)bv.x, (_Float16)bv.y, (_Float16)bv.z, (_Float16)bv.w };
            *(half4*)(Bs + row * 40 + col) = bh;
        }
        __syncthreads();
        half8 af[4], bf[4];
#pragma unroll
        for (int mt = 0; mt < 4; ++mt)
            af[mt] = *(const half8*)(As + (wm * 64 + mt * 16 + l15) * 40 + koff);
#pragma unroll
        for (int nt = 0; nt < 4; ++nt)
            bf[nt] = *(const half8*)(Bs + (wn * 64 + nt * 16 + l15) * 40 + koff);
#pragma unroll
        for (int mt = 0; mt < 4; ++mt)
#pragma unroll
            for (int nt = 0; nt < 4; ++nt)
                acc[mt][nt] = __builtin_amdgcn_mfma_f32_16x16x32_f16(af[mt], bf[nt], acc[mt][nt], 0, 0, 0);
    }

    const int rbase = (lane >> 4) << 2;
#pragma unroll
    for (int mt = 0; mt < 4; ++mt)
#pragma unroll
        for (int nt = 0; nt < 4; ++nt) {
            int gn = n0 + wn * 64 + nt * 16 + l15;
            float bb = bias[gn];
#pragma unroll
            for (int r = 0; r < 4; ++r) {
                int gm = m0 + wm * 64 + mt * 16 + rbase + r;
                out[(size_t)gm * CEMB + gn] = acc[mt][nt][r] + bb;
            }
        }
}

// ---------------------------------------------------------------------------
extern "C" void kernel_launch(void* const* d_in, const int* in_sizes, int n_in,
                              void* d_out, int out_size, void* d_ws, size_t ws_size,
                              hipStream_t stream) {
    const float* x     = (const float*)d_in[0];   // [B,T,C]
    const float* Wattn = (const float*)d_in[1];   // [3C,C]
    const float* Wproj = (const float*)d_in[2];   // [C,C]
    const float* bproj = (const float*)d_in[3];   // [C]
    float* out = (float*)d_out;

    const size_t per = (size_t)BATCH * NHEAD * TSEQ * HD;   // 8,388,608 elems
    _Float16* q16    = (_Float16*)d_ws;
    _Float16* k16    = q16 + per;
    _Float16* v16    = k16 + per;
    _Float16* attn16 = v16 + per;
    // total ws use: 4 * per * 2 B = 64 MiB

    qkv_gemm<<<dim3(3 * CEMB / 128, MROWS / 128), 256, 0, stream>>>(x, Wattn, q16, k16, v16);
    attn_fwd<<<dim3(TSEQ / 64, BATCH * NHEAD), 256, 0, stream>>>(q16, k16, v16, attn16);
    proj_gemm<<<dim3(CEMB / 128, MROWS / 128), 256, 0, stream>>>(attn16, Wproj, bproj, out);
}

// Round 2
// 350.572 us; speedup vs baseline: 1.3867x; 1.3867x over previous
//
#include <hip/hip_runtime.h>
#include <math.h>

#define BATCH 4
#define TSEQ  2048
#define CEMB  1024
#define NHEAD 16
#define HD    64
#define MROWS (BATCH * TSEQ)   // 8192

typedef _Float16 half8 __attribute__((ext_vector_type(8)));
typedef _Float16 half4 __attribute__((ext_vector_type(4)));
typedef float    floatx4 __attribute__((ext_vector_type(4)));

#define GLOBAL_AS __attribute__((address_space(1)))
#define LDS_AS    __attribute__((address_space(3)))

// async global->LDS DMA, 16 B per lane. LDS dest = wave-uniform base + lane*16.
__device__ __forceinline__ void lds_dma16(const _Float16* g, _Float16* l) {
    __builtin_amdgcn_global_load_lds((const GLOBAL_AS unsigned int*)g,
                                     (LDS_AS unsigned int*)l, 16, 0, 0);
}

// ---------------------------------------------------------------------------
// Kernel 0: fp32 -> fp16 convert prepass for x, W_attn, W_proj (float4->half4)
// ---------------------------------------------------------------------------
__global__ __launch_bounds__(256)
void cvt_fp16(const float* __restrict__ x, const float* __restrict__ wa,
              const float* __restrict__ wp, _Float16* __restrict__ x16,
              _Float16* __restrict__ wa16, _Float16* __restrict__ wp16)
{
    const int n1 = (BATCH * TSEQ * CEMB) / 4;   // 2,097,152 float4s
    const int n2 = (3 * CEMB * CEMB) / 4;       //   786,432
    int i = blockIdx.x * 256 + threadIdx.x;
    const float* src; _Float16* dst; int j;
    if (i < n1)            { src = x;  dst = x16;  j = i; }
    else if (i < n1 + n2)  { src = wa; dst = wa16; j = i - n1; }
    else                   { src = wp; dst = wp16; j = i - n1 - n2; }
    float4 v = ((const float4*)src)[j];
    half4 h = { (_Float16)v.x, (_Float16)v.y, (_Float16)v.z, (_Float16)v.w };
    ((half4*)dst)[j] = h;
}

// ---------------------------------------------------------------------------
// GEMM core pieces: 128x128 tile, BK=32, global_load_lds staging with
// XOR-swizzled 16B chunks (pc = chunk ^ ((row>>1)&3)) for conflict-free reads.
// ---------------------------------------------------------------------------
__device__ __forceinline__ void stage_tile(const _Float16* __restrict__ gbase,
                                           _Float16* __restrict__ lds,
                                           int row0, int kk, int tid)
{
#pragma unroll
    for (int p = 0; p < 2; ++p) {
        int ci  = p * 256 + tid;       // physical chunk 0..511 (4 chunks/row)
        int row = ci >> 2, pc = ci & 3;
        int gc  = pc ^ ((row >> 1) & 3);
        lds_dma16(gbase + (size_t)(row0 + row) * CEMB + kk + gc * 8, lds + ci * 8);
    }
}

// ---------------------------------------------------------------------------
// Kernel 1: qkv = x16 @ Wa16^T; scatter epilogue to q/k (row) and v (col-major)
// ---------------------------------------------------------------------------
__global__ __launch_bounds__(256)
void qkv_gemm(const _Float16* __restrict__ A, const _Float16* __restrict__ B,
              _Float16* __restrict__ q16, _Float16* __restrict__ k16,
              _Float16* __restrict__ v16)
{
    __shared__ __align__(16) _Float16 As[128 * 32];
    __shared__ __align__(16) _Float16 Bs[128 * 32];
    const int tid = threadIdx.x, lane = tid & 63, wave = tid >> 6;
    const int wm = wave & 1, wn = wave >> 1;
    const int m0 = blockIdx.y * 128, n0 = blockIdx.x * 128;
    const int l15 = lane & 15, quad = lane >> 4;
    const int sw = (l15 >> 1) & 3;

    floatx4 acc[4][4];
#pragma unroll
    for (int i = 0; i < 4; ++i)
#pragma unroll
        for (int j = 0; j < 4; ++j) acc[i][j] = (floatx4){0.f, 0.f, 0.f, 0.f};

    for (int kk = 0; kk < CEMB; kk += 32) {
        __syncthreads();
        stage_tile(A, As, m0, kk, tid);
        stage_tile(B, Bs, n0, kk, tid);
        __syncthreads();   // compiler emits vmcnt(0) drain here
        half8 af[4], bf[4];
#pragma unroll
        for (int mt = 0; mt < 4; ++mt)
            af[mt] = *(const half8*)(As + (wm * 64 + mt * 16 + l15) * 32 + ((quad ^ sw) << 3));
#pragma unroll
        for (int nt = 0; nt < 4; ++nt)
            bf[nt] = *(const half8*)(Bs + (wn * 64 + nt * 16 + l15) * 32 + ((quad ^ sw) << 3));
#pragma unroll
        for (int mt = 0; mt < 4; ++mt)
#pragma unroll
            for (int nt = 0; nt < 4; ++nt)
                acc[mt][nt] = __builtin_amdgcn_mfma_f32_16x16x32_f16(af[mt], bf[nt], acc[mt][nt], 0, 0, 0);
    }

    const int rbase = quad << 2;
#pragma unroll
    for (int mt = 0; mt < 4; ++mt) {
#pragma unroll
        for (int nt = 0; nt < 4; ++nt) {
            int gn = n0 + wn * 64 + nt * 16 + l15;
#pragma unroll
            for (int r = 0; r < 4; ++r) {
                int gm = m0 + wm * 64 + mt * 16 + rbase + r;
                _Float16 hv = (_Float16)acc[mt][nt][r];
                int b = gm >> 11, t = gm & (TSEQ - 1);
                if (gn < CEMB) {
                    int h = gn >> 6, d = gn & 63;
                    q16[(((size_t)(b * NHEAD + h)) * TSEQ + t) * HD + d] = hv;
                } else if (gn < 2 * CEMB) {
                    int c2 = gn - CEMB;
                    int h = c2 >> 6, d = c2 & 63;
                    k16[(((size_t)(b * NHEAD + h)) * TSEQ + t) * HD + d] = hv;
                } else {
                    int c2 = gn - 2 * CEMB;
                    int h = c2 >> 6, d = c2 & 63;
                    v16[(((size_t)(b * NHEAD + h)) * HD + d) * TSEQ + t] = hv;  // V^T
                }
            }
        }
    }
}

// ---------------------------------------------------------------------------
// Kernel 2: flash attention, paired q-tiles (x, 31-x) per block for perfect
// load balance; K/V staging shared; Q register-resident; per-wave P transpose
// with XOR-by-quad swizzle + lgkmcnt wait (no block barrier).
// ---------------------------------------------------------------------------
__device__ __forceinline__ void attn_tile(
    const half8& q0, const half8& q1,
    float (&m_i)[4], float (&l_i)[4], floatx4 (&o)[4],
    const _Float16* __restrict__ Ks, const _Float16* __restrict__ Vs,
    _Float16* __restrict__ pw, bool domask, int l15, int quad, int relrow)
{
    floatx4 s[4];
#pragma unroll
    for (int nt = 0; nt < 4; ++nt) {
        half8 kf0 = *(const half8*)(Ks + (nt * 16 + l15) * 72 + quad * 8);
        half8 kf1 = *(const half8*)(Ks + (nt * 16 + l15) * 72 + 32 + quad * 8);
        floatx4 z = (floatx4){0.f, 0.f, 0.f, 0.f};
        z = __builtin_amdgcn_mfma_f32_16x16x32_f16(q0, kf0, z, 0, 0, 0);
        z = __builtin_amdgcn_mfma_f32_16x16x32_f16(q1, kf1, z, 0, 0, 0);
        s[nt] = z;
    }
    if (domask) {
#pragma unroll
        for (int nt = 0; nt < 4; ++nt)
#pragma unroll
            for (int r = 0; r < 4; ++r) {
                float sv = s[nt][r] * 8.0f;
                if (nt * 16 + l15 > relrow + r) sv = -INFINITY;
                s[nt][r] = sv;
            }
    } else {
#pragma unroll
        for (int nt = 0; nt < 4; ++nt)
#pragma unroll
            for (int r = 0; r < 4; ++r) s[nt][r] *= 8.0f;
    }
    float alpha[4];
#pragma unroll
    for (int r = 0; r < 4; ++r) {
        float v = fmaxf(fmaxf(s[0][r], s[1][r]), fmaxf(s[2][r], s[3][r]));
#pragma unroll
        for (int off = 1; off < 16; off <<= 1)
            v = fmaxf(v, __shfl_xor(v, off, 64));
        float mn = fmaxf(m_i[r], v);
        alpha[r] = __expf(m_i[r] - mn);
        m_i[r] = mn;
    }
    float rsum[4] = {0.f, 0.f, 0.f, 0.f};
#pragma unroll
    for (int nt = 0; nt < 4; ++nt)
#pragma unroll
        for (int r = 0; r < 4; ++r) {
            float p = __expf(s[nt][r] - m_i[r]);
            s[nt][r] = p;
            rsum[r] += p;
        }
#pragma unroll
    for (int r = 0; r < 4; ++r) {
        float v = rsum[r];
#pragma unroll
        for (int off = 1; off < 16; off <<= 1)
            v += __shfl_xor(v, off, 64);
        l_i[r] = l_i[r] * alpha[r] + v;
    }
#pragma unroll
    for (int nt = 0; nt < 4; ++nt)
#pragma unroll
        for (int r = 0; r < 4; ++r) o[nt][r] *= alpha[r];

    // P: C-layout -> A-layout, per-wave LDS, XOR-by-quad column swizzle
#pragma unroll
    for (int nt = 0; nt < 4; ++nt)
#pragma unroll
        for (int r = 0; r < 4; ++r)
            pw[(quad * 4 + r) * 72 + ((nt * 16 + l15) ^ (quad << 4))] = (_Float16)s[nt][r];
    asm volatile("s_waitcnt lgkmcnt(0)" ::: "memory");
    const int xk = (l15 >> 2) & 3;
    half8 pf0 = *(const half8*)(pw + l15 * 72 + ((quad * 8) ^ (xk << 4)));
    half8 pf1 = *(const half8*)(pw + l15 * 72 + ((32 + quad * 8) ^ (xk << 4)));
#pragma unroll
    for (int nt = 0; nt < 4; ++nt) {
        half8 vf0 = *(const half8*)(Vs + (nt * 16 + l15) * 72 + quad * 8);
        half8 vf1 = *(const half8*)(Vs + (nt * 16 + l15) * 72 + 32 + quad * 8);
        o[nt] = __builtin_amdgcn_mfma_f32_16x16x32_f16(pf0, vf0, o[nt], 0, 0, 0);
        o[nt] = __builtin_amdgcn_mfma_f32_16x16x32_f16(pf1, vf1, o[nt], 0, 0, 0);
    }
}

__global__ __launch_bounds__(256, 4)
void attn_fwd(const _Float16* __restrict__ q16, const _Float16* __restrict__ k16,
              const _Float16* __restrict__ v16, _Float16* __restrict__ o16)
{
    __shared__ __align__(16) _Float16 Ks[64 * 72];
    __shared__ __align__(16) _Float16 Vs[64 * 72];
    __shared__ __align__(16) _Float16 Ps[8 * 16 * 72];
    const int tid = threadIdx.x, lane = tid & 63, wave = tid >> 6;
    const int l15 = lane & 15, quad = lane >> 4;
    const int qtA = blockIdx.x;        // 0..15
    const int qtB = 31 - qtA;          // 31..16
    const int bh = blockIdx.y, b = bh >> 4, h = bh & 15;
    const int q0A = qtA * 64, q0B = qtB * 64;
    const _Float16* qp = q16 + (size_t)bh * TSEQ * HD;
    const _Float16* kp = k16 + (size_t)bh * TSEQ * HD;
    const _Float16* vp = v16 + (size_t)bh * HD * TSEQ;

    const int qrl = wave * 16 + l15;
    half8 qA0 = *(const half8*)(qp + (size_t)(q0A + qrl) * HD + quad * 8);
    half8 qA1 = *(const half8*)(qp + (size_t)(q0A + qrl) * HD + 32 + quad * 8);
    half8 qB0 = *(const half8*)(qp + (size_t)(q0B + qrl) * HD + quad * 8);
    half8 qB1 = *(const half8*)(qp + (size_t)(q0B + qrl) * HD + 32 + quad * 8);

    float mA[4], lA[4], mB[4], lB[4];
    floatx4 oA[4], oB[4];
#pragma unroll
    for (int r = 0; r < 4; ++r) { mA[r] = -INFINITY; lA[r] = 0.f; mB[r] = -INFINITY; lB[r] = 0.f; }
#pragma unroll
    for (int nt = 0; nt < 4; ++nt) { oA[nt] = (floatx4){0.f,0.f,0.f,0.f}; oB[nt] = (floatx4){0.f,0.f,0.f,0.f}; }

    _Float16* pwA = Ps + wave * (16 * 72);
    _Float16* pwB = Ps + (4 + wave) * (16 * 72);
    const int relrow = wave * 16 + (quad << 2);

    for (int kt = 0; kt <= qtB; ++kt) {
        const int kt0 = kt * 64;
        __syncthreads();
#pragma unroll
        for (int i = 0; i < 2; ++i) {
            int c = tid + i * 256;
            int row = c >> 3, ch = (c & 7) << 3;
            *(half8*)(Ks + row * 72 + ch) = *(const half8*)(kp + (size_t)(kt0 + row) * HD + ch);
            *(half8*)(Vs + row * 72 + ch) = *(const half8*)(vp + (size_t)row * TSEQ + kt0 + ch);
        }
        __syncthreads();
        attn_tile(qB0, qB1, mB, lB, oB, Ks, Vs, pwB, (kt == qtB), l15, quad, relrow);
        if (kt <= qtA)
            attn_tile(qA0, qA1, mA, lA, oA, Ks, Vs, pwA, (kt == qtA), l15, quad, relrow);
    }

    // epilogue: normalize + store [B,T,C] fp16 for both tiles
#pragma unroll
    for (int nt = 0; nt < 4; ++nt)
#pragma unroll
        for (int r = 0; r < 4; ++r) {
            int d = nt * 16 + l15;
            int tA = q0A + relrow + r;
            int tB = q0B + relrow + r;
            o16[((size_t)(b * TSEQ + tA)) * CEMB + h * HD + d] = (_Float16)(oA[nt][r] / lA[r]);
            o16[((size_t)(b * TSEQ + tB)) * CEMB + h * HD + d] = (_Float16)(oB[nt][r] / lB[r]);
        }
}

// ---------------------------------------------------------------------------
// Kernel 3: y = attn16 @ Wp16^T + b_proj, fp32 out
// ---------------------------------------------------------------------------
__global__ __launch_bounds__(256)
void proj_gemm(const _Float16* __restrict__ A, const _Float16* __restrict__ B,
               const float* __restrict__ bias, float* __restrict__ out)
{
    __shared__ __align__(16) _Float16 As[128 * 32];
    __shared__ __align__(16) _Float16 Bs[128 * 32];
    const int tid = threadIdx.x, lane = tid & 63, wave = tid >> 6;
    const int wm = wave & 1, wn = wave >> 1;
    const int m0 = blockIdx.y * 128, n0 = blockIdx.x * 128;
    const int l15 = lane & 15, quad = lane >> 4;
    const int sw = (l15 >> 1) & 3;

    floatx4 acc[4][4];
#pragma unroll
    for (int i = 0; i < 4; ++i)
#pragma unroll
        for (int j = 0; j < 4; ++j) acc[i][j] = (floatx4){0.f, 0.f, 0.f, 0.f};

    for (int kk = 0; kk < CEMB; kk += 32) {
        __syncthreads();
        stage_tile(A, As, m0, kk, tid);
        stage_tile(B, Bs, n0, kk, tid);
        __syncthreads();
        half8 af[4], bf[4];
#pragma unroll
        for (int mt = 0; mt < 4; ++mt)
            af[mt] = *(const half8*)(As + (wm * 64 + mt * 16 + l15) * 32 + ((quad ^ sw) << 3));
#pragma unroll
        for (int nt = 0; nt < 4; ++nt)
            bf[nt] = *(const half8*)(Bs + (wn * 64 + nt * 16 + l15) * 32 + ((quad ^ sw) << 3));
#pragma unroll
        for (int mt = 0; mt < 4; ++mt)
#pragma unroll
            for (int nt = 0; nt < 4; ++nt)
                acc[mt][nt] = __builtin_amdgcn_mfma_f32_16x16x32_f16(af[mt], bf[nt], acc[mt][nt], 0, 0, 0);
    }

    const int rbase = quad << 2;
#pragma unroll
    for (int mt = 0; mt < 4; ++mt)
#pragma unroll
        for (int nt = 0; nt < 4; ++nt) {
            int gn = n0 + wn * 64 + nt * 16 + l15;
            float bb = bias[gn];
#pragma unroll
            for (int r = 0; r < 4; ++r) {
                int gm = m0 + wm * 64 + mt * 16 + rbase + r;
                out[(size_t)gm * CEMB + gn] = acc[mt][nt][r] + bb;
            }
        }
}

// ---------------------------------------------------------------------------
extern "C" void kernel_launch(void* const* d_in, const int* in_sizes, int n_in,
                              void* d_out, int out_size, void* d_ws, size_t ws_size,
                              hipStream_t stream) {
    const float* x     = (const float*)d_in[0];   // [B,T,C]
    const float* Wattn = (const float*)d_in[1];   // [3C,C]
    const float* Wproj = (const float*)d_in[2];   // [C,C]
    const float* bproj = (const float*)d_in[3];   // [C]
    float* out = (float*)d_out;

    const size_t nx  = (size_t)BATCH * TSEQ * CEMB;   // 8,388,608
    const size_t nwa = (size_t)3 * CEMB * CEMB;       // 3,145,728
    const size_t nwp = (size_t)CEMB * CEMB;           // 1,048,576
    const size_t per = (size_t)BATCH * NHEAD * TSEQ * HD;  // 8,388,608

    _Float16* x16    = (_Float16*)d_ws;
    _Float16* wa16   = x16 + nx;
    _Float16* wp16   = wa16 + nwa;
    _Float16* q16    = wp16 + nwp;
    _Float16* k16    = q16 + per;
    _Float16* v16    = k16 + per;
    _Float16* attn16 = x16;   // alias: x16 fully consumed by qkv_gemm before attn writes
    // total ws: (nx + nwa + nwp + 3*per) * 2 B ~= 75.5 MiB

    const int nconv = (int)((nx + nwa + nwp) / 4);    // float4 count = 3,145,728
    cvt_fp16<<<nconv / 256, 256, 0, stream>>>(x, Wattn, Wproj, x16, wa16, wp16);
    qkv_gemm<<<dim3(3 * CEMB / 128, MROWS / 128), 256, 0, stream>>>(x16, wa16, q16, k16, v16);
    attn_fwd<<<dim3(16, BATCH * NHEAD), 256, 0, stream>>>(q16, k16, v16, attn16);
    proj_gemm<<<dim3(CEMB / 128, MROWS / 128), 256, 0, stream>>>(attn16, wp16, bproj, out);
}